// Round 1
// baseline (320.607 us; speedup 1.0000x reference)
//
#include <hip/hip_runtime.h>
#include <math.h>

#define D_DIM 2048
#define NE    64
#define NTOK  16384
#define TK    8
#define TOKB  64                  // tokens per block (and per wave)
#define KS    8                   // K-split: 8 waves per block, 256 d each
#define KD    (D_DIM / KS)        // 256
#define KCH   16                  // d per chunk per wave
#define NCH   (KD / KCH)          // 16 chunks
#define BT    512                 // threads per block

#define XS_BUF_FLOATS (KS * TOKB * KCH)        // 8192 floats = 32 KB per buffer
#define RED_ROW       72                       // 64 + 8 pad (bank-spread partials)
#define POOL_FLOATS   (KS * TOKB * RED_ROW)    // 36864 floats = 144 KB

#define OUT_I_OFF (NTOK * TK)
#define OUT_S_OFF (2 * NTOK * TK)

#define GLOBAL_AS __attribute__((address_space(1)))
#define LDS_AS    __attribute__((address_space(3)))

static __device__ __forceinline__ void async_copy16(const float* g, float* l) {
    __builtin_amdgcn_global_load_lds((const GLOBAL_AS void*)g, (LDS_AS void*)l, 16, 0, 0);
}

// ---------------- kernel 1: scores = sigmoid(x.w^T) + gb ----------------
// Block = 8 waves, wave = K-split ks (256 d). Lane (lt = lane>>3, le = lane&7).
// Per lane: 8 tokens (t_i = i*8+lt) x 8 experts (e_j = j*8+le) accumulator tile.
// x: global_load_lds staged, quad-XOR-swizzled; reads are 8-distinct-quad
//    broadcasts (2-way bank aliasing = free). w: per-lane divergent float4
//    global loads (L2-resident, vmcnt path, NOT scalarized -> no SMEM serialization).
__global__ __launch_bounds__(BT, 2) void gate_gemm(const float* __restrict__ x,
                                                   const float* __restrict__ w,
                                                   const float* __restrict__ gb,
                                                   float* __restrict__ scores) {
    __shared__ __align__(16) float pool[POOL_FLOATS];   // xs dbuf (64 KB) then partials (144 KB)

    const int tid  = threadIdx.x;
    const int lane = tid & 63;
    const int ks   = tid >> 6;     // wave id = K split (0..7)
    const int lt   = lane >> 3;    // token slot (0..7)
    const int le   = lane & 7;     // expert slot (0..7)
    const int tok0 = blockIdx.x * TOKB;
    const int lt3  = lt & 3;

    // w row pointers: e_j = j*8 + le, this wave's d-range. Divergent (le) -> vector loads.
    const float4* wp[8];
#pragma unroll
    for (int j = 0; j < 8; ++j)
        wp[j] = (const float4*)(w + (size_t)(j * 8 + le) * D_DIM + ks * KD);

    // staging: 4 x 16B quads per thread per chunk. Linear LDS dest; XOR swizzle
    // applied on the GLOBAL source side (slot s holds logical quad s ^ (t&3)).
    const float* srcb[4];
#pragma unroll
    for (int k = 0; k < 4; ++k) {
        int qq  = tid + k * BT;        // quad index 0..2047: [ks][t][slot]
        int kss = qq >> 8;
        int r   = qq & 255;
        int ts  = r >> 2;
        int s   = r & 3;
        int dqs = s ^ (ts & 3);
        srcb[k] = x + (size_t)(tok0 + ts) * D_DIM + kss * KD + dqs * 4;
    }

    auto stage = [&](int c, int buf) {
        float* dst = pool + buf * XS_BUF_FLOATS + tid * 4;
#pragma unroll
        for (int k = 0; k < 4; ++k)
            async_copy16(srcb[k] + c * KCH, dst + k * (BT * 4));
    };

    float acc[8][8];
#pragma unroll
    for (int i = 0; i < 8; ++i)
#pragma unroll
        for (int j = 0; j < 8; ++j) acc[i][j] = 0.f;

    float4 wa[8], wb[8];
#pragma unroll
    for (int j = 0; j < 8; ++j) wa[j] = wp[j][0];     // quad 0 of this wave's range
    stage(0, 0);

    // one K-step: FMA on WC (resident), prefetch next quad into WN (vmcnt),
    // x via 8 ds_read_b128 broadcasts (lgkmcnt only - no SMEM in the loop).
    auto step = [&](float4 (&WC)[8], float4 (&WN)[8], int c, int dq) {
        const int c4n = (c * 4 + dq + 1) & 63;        // next float4 index (wraps, unused on last)
#pragma unroll
        for (int j = 0; j < 8; ++j) WN[j] = wp[j][c4n];
        const float* xb = pool + (c & 1) * XS_BUF_FLOATS + ks * (TOKB * KCH)
                        + lt * KCH + ((dq ^ lt3) << 2);
        float4 xi[8];
#pragma unroll
        for (int i = 0; i < 8; ++i)
            xi[i] = *(const float4*)(xb + i * (8 * KCH));
#pragma unroll
        for (int i = 0; i < 8; ++i) {
#pragma unroll
            for (int j = 0; j < 8; ++j) {
                acc[i][j] = fmaf(xi[i].x, WC[j].x, acc[i][j]);
                acc[i][j] = fmaf(xi[i].y, WC[j].y, acc[i][j]);
                acc[i][j] = fmaf(xi[i].z, WC[j].z, acc[i][j]);
                acc[i][j] = fmaf(xi[i].w, WC[j].w, acc[i][j]);
            }
        }
    };

    for (int c = 0; c < NCH; ++c) {
        __syncthreads();                          // chunk-c staging drained (vmcnt@barrier)
        if (c + 1 < NCH) stage(c + 1, (c + 1) & 1);
        step(wa, wb, c, 0);
        step(wb, wa, c, 1);
        step(wa, wb, c, 2);
        step(wb, wa, c, 3);
    }

    // ---- split-K reduction: partials -> LDS (padded rows: 2-way aliasing only)
    __syncthreads();                              // all xs reads done; reuse pool
    {
        const int rb = ks * (TOKB * RED_ROW);
#pragma unroll
        for (int i = 0; i < 8; ++i)
#pragma unroll
            for (int j = 0; j < 8; ++j)
                pool[rb + (i * 8 + lt) * RED_ROW + j * 8 + le] = acc[i][j];
    }
    __syncthreads();
    {
        const int t = tid >> 3;                   // token 0..63
        const int q = tid & 7;                    // expert-octet 0..7
        float s[8];
#pragma unroll
        for (int u = 0; u < 8; ++u) s[u] = 0.f;
#pragma unroll
        for (int k = 0; k < KS; ++k) {
            const float* rp = pool + k * (TOKB * RED_ROW) + t * RED_ROW + q * 8;
            float4 a = *(const float4*)rp;
            float4 b = *(const float4*)(rp + 4);
            s[0] += a.x; s[1] += a.y; s[2] += a.z; s[3] += a.w;
            s[4] += b.x; s[5] += b.y; s[6] += b.z; s[7] += b.w;
        }
        float4 g0 = *(const float4*)(gb + q * 8);
        float4 g1 = *(const float4*)(gb + q * 8 + 4);
        float r[8];
        r[0] = 1.f / (1.f + expf(-s[0])) + g0.x;
        r[1] = 1.f / (1.f + expf(-s[1])) + g0.y;
        r[2] = 1.f / (1.f + expf(-s[2])) + g0.z;
        r[3] = 1.f / (1.f + expf(-s[3])) + g0.w;
        r[4] = 1.f / (1.f + expf(-s[4])) + g1.x;
        r[5] = 1.f / (1.f + expf(-s[5])) + g1.y;
        r[6] = 1.f / (1.f + expf(-s[6])) + g1.z;
        r[7] = 1.f / (1.f + expf(-s[7])) + g1.w;
        float* so = scores + (size_t)(tok0 + t) * NE + q * 8;
        float4 v0 = {r[0], r[1], r[2], r[3]};
        float4 v1 = {r[4], r[5], r[6], r[7]};
        ((float4*)so)[0] = v0;
        ((float4*)so)[1] = v1;
    }
}

// ---------- kernel 2: top-8 + normalize (ties -> lower index; unchanged) ----------
__global__ __launch_bounds__(256) void topk_kernel(const float* __restrict__ scores,
                                                   float* __restrict__ out) {
    const int tid = threadIdx.x;
    const int t   = blockIdx.x * 64 + (tid >> 2);
    const int q   = tid & 3;
    float v[16];
    const float4* sp = (const float4*)(scores + (size_t)t * NE + q * 16);
    float4 a = sp[0], b = sp[1], c = sp[2], d = sp[3];
    v[0] = a.x;  v[1] = a.y;  v[2] = a.z;  v[3] = a.w;
    v[4] = b.x;  v[5] = b.y;  v[6] = b.z;  v[7] = b.w;
    v[8] = c.x;  v[9] = c.y;  v[10] = c.z; v[11] = c.w;
    v[12] = d.x; v[13] = d.y; v[14] = d.z; v[15] = d.w;

    float kv[TK]; int ki[TK];
#pragma unroll
    for (int k = 0; k < TK; ++k) {
        float bv = v[0]; int bi = q * 16;
#pragma unroll
        for (int j = 1; j < 16; ++j) {
            bool gt = v[j] > bv;
            bv = gt ? v[j] : bv;
            bi = gt ? (q * 16 + j) : bi;
        }
#pragma unroll
        for (int off = 1; off < 4; off <<= 1) {
            float ov = __shfl_xor(bv, off);
            int   oi = __shfl_xor(bi, off);
            bool take = (ov > bv) || (ov == bv && oi < bi);
            bv = take ? ov : bv;
            bi = take ? oi : bi;
        }
        int lj = bi - q * 16;
#pragma unroll
        for (int j = 0; j < 16; ++j) v[j] = (j == lj) ? -3e38f : v[j];
        kv[k] = bv; ki[k] = bi;
    }

    if (q == 0) {
        float s = 0.f;
#pragma unroll
        for (int k = 0; k < TK; ++k) s += kv[k];
        float inv = 1.f / s;
        float* ow = out + (size_t)t * TK;
        float* oi = out + OUT_I_OFF + (size_t)t * TK;
#pragma unroll
        for (int k = 0; k < TK; ++k) {
            ow[k] = kv[k] * inv;
            oi[k] = (float)ki[k];
        }
    }
}

extern "C" void kernel_launch(void* const* d_in, const int* in_sizes, int n_in,
                              void* d_out, int out_size, void* d_ws, size_t ws_size,
                              hipStream_t stream) {
    const float* x  = (const float*)d_in[0];
    const float* w  = (const float*)d_in[1];
    const float* gb = (const float*)d_in[2];
    float* out    = (float*)d_out;
    float* scores = out + OUT_S_OFF;
    (void)in_sizes; (void)n_in; (void)out_size; (void)d_ws; (void)ws_size;

    gate_gemm<<<dim3(NTOK / TOKB), dim3(BT), 0, stream>>>(x, w, gb, scores);
    topk_kernel<<<dim3(NTOK / 64), dim3(256), 0, stream>>>(scores, out);
}